// Round 5
// baseline (665.672 us; speedup 1.0000x reference)
//
#include <hip/hip_runtime.h>

#define N_NODES 100000
#define N_EDGES 1200000
#define NB_SCAN ((N_NODES + 1023) / 1024)   // 98 blocks of 1024 elements
// D_IN = D_HID = 64, D_OUT = 16

// ---------------------------------------------------------------------------
// CSR build: deg histogram -> exclusive scan (3 tiny kernels) -> cursor fill.
// ---------------------------------------------------------------------------
__global__ __launch_bounds__(256) void k_hist(const int* __restrict__ ei,
                                              int* __restrict__ deg) {
    int e = blockIdx.x * 256 + threadIdx.x;
    if (e < N_EDGES) atomicAdd(&deg[ei[N_EDGES + e]], 1);
}

__global__ __launch_bounds__(256) void k_scanA(const int* __restrict__ deg,
                                               int* __restrict__ bsum) {
    const int b = blockIdx.x, t = threadIdx.x;
    const int base = b * 1024 + t * 4;
    int s = 0;
    #pragma unroll
    for (int i = 0; i < 4; ++i) {
        int idx = base + i;
        if (idx < N_NODES) s += deg[idx];
    }
    #pragma unroll
    for (int off = 1; off < 64; off <<= 1) s += __shfl_xor(s, off);
    __shared__ int part[4];
    if ((t & 63) == 0) part[t >> 6] = s;
    __syncthreads();
    if (t == 0) bsum[b] = part[0] + part[1] + part[2] + part[3];
}

__global__ void k_scanB(const int* __restrict__ bsum, int* __restrict__ boff) {
    if (threadIdx.x == 0) {
        int acc = 0;
        for (int i = 0; i < NB_SCAN; ++i) { boff[i] = acc; acc += bsum[i]; }
    }
}

__global__ __launch_bounds__(256) void k_scanC(const int* __restrict__ deg,
                                               const int* __restrict__ boff,
                                               int* __restrict__ row_ptr) {
    __shared__ int tot[256];
    const int b = blockIdx.x, t = threadIdx.x;
    const int base = b * 1024 + t * 4;
    int d[4]; int s = 0;
    #pragma unroll
    for (int i = 0; i < 4; ++i) {
        int idx = base + i;
        d[i] = (idx < N_NODES) ? deg[idx] : 0;
        s += d[i];
    }
    tot[t] = s;
    __syncthreads();
    for (int off = 1; off < 256; off <<= 1) {
        int v = (t >= off) ? tot[t - off] : 0;
        __syncthreads();
        tot[t] += v;
        __syncthreads();
    }
    int run = boff[b] + tot[t] - s;   // exclusive prefix for this thread
    #pragma unroll
    for (int i = 0; i < 4; ++i) {
        int idx = base + i;
        if (idx < N_NODES) { row_ptr[idx] = run; run += d[i]; }
    }
    if (b == 0 && t == 0) row_ptr[N_NODES] = N_EDGES;
}

__global__ __launch_bounds__(256) void k_fill(const int* __restrict__ ei,
                                              const float* __restrict__ ew,
                                              int* __restrict__ cursor,
                                              uint2* __restrict__ csr) {
    int e = blockIdx.x * 256 + threadIdx.x;
    if (e < N_EDGES) {
        int src = ei[e];
        int dst = ei[N_EDGES + e];
        int pos = atomicAdd(&cursor[dst], 1);
        csr[pos] = make_uint2((unsigned)src, __float_as_uint(ew[e]));
    }
}

// ---------------------------------------------------------------------------
// k_l1: fused layer-1 gather + node update.
// Gather: 16-lane groups, lane holds float4 of the 64-dim row (dims jj..jj+3);
// group g takes edges r0+g, r0+g+4, ...; unroll 4 with clamped index +
// zero-weight for OOB -> branchless, up to 16 outstanding x-row loads/wave.
// Then xor-combine groups, and the wave does the full node update in regs:
//   h = relu(mean @ W1l + x[n] @ W1r + b1); z2 = h@W2l; hw2r = h@W2r
// ---------------------------------------------------------------------------
__global__ __launch_bounds__(512, 4) void k_l1(const float* __restrict__ x,
                                               const int* __restrict__ row_ptr,
                                               const uint2* __restrict__ csr,
                                               const float* __restrict__ W1l,
                                               const float* __restrict__ b1,
                                               const float* __restrict__ W1r,
                                               const float* __restrict__ W2l,
                                               const float* __restrict__ W2r,
                                               float* __restrict__ z2,
                                               float* __restrict__ hw2r) {
    __shared__ float w1l[64 * 64];
    __shared__ float w1r[64 * 64];
    __shared__ float w2l[64 * 17];   // stride-17: 4-way bank conflict -> 2-way
    __shared__ float w2r[64 * 17];
    for (int i = threadIdx.x; i < 64 * 64; i += 512) { w1l[i] = W1l[i]; w1r[i] = W1r[i]; }
    for (int i = threadIdx.x; i < 64 * 16; i += 512) {
        int k = i >> 4, j = i & 15;
        w2l[k * 17 + j] = W2l[i];
        w2r[k * 17 + j] = W2r[i];
    }
    __syncthreads();
    const int lane = threadIdx.x & 63;
    const int wid  = blockIdx.x * 8 + (threadIdx.x >> 6);
    const int nw   = gridDim.x * 8;
    const int j = lane & 15, g = lane >> 4;
    const int jj = (lane & 15) * 4;          // this lane's dim chunk
    const float b1v = b1[lane];              // bias in reg (not LDS)
    for (int n = wid; n < N_NODES; n += nw) {
        const int r0 = row_ptr[n], r1 = row_ptr[n + 1];
        const int deg = r1 - r0;
        float ax = 0.f, ay = 0.f, az0 = 0.f, aw = 0.f;
        for (int i0 = r0; i0 < r1; i0 += 16) {
            const int rmax = r1 - 1;
            uint2 e[4]; float wt[4];
            #pragma unroll
            for (int u = 0; u < 4; ++u) {
                int idx = i0 + g + u * 4;
                int idc = idx < rmax ? idx : rmax;   // clamp (valid addr)
                e[u]  = csr[idc];
                wt[u] = (idx < r1) ? __uint_as_float(e[u].y) : 0.f;
            }
            float4 xv[4];
            #pragma unroll
            for (int u = 0; u < 4; ++u)
                xv[u] = *(const float4*)&x[(size_t)e[u].x * 64 + jj];
            #pragma unroll
            for (int u = 0; u < 4; ++u) {
                ax  = fmaf(xv[u].x, wt[u], ax);
                ay  = fmaf(xv[u].y, wt[u], ay);
                az0 = fmaf(xv[u].z, wt[u], az0);
                aw  = fmaf(xv[u].w, wt[u], aw);
            }
        }
        // combine the 4 lane-groups (each summed a different edge subset)
        ax  += __shfl_xor(ax, 16);  ax  += __shfl_xor(ax, 32);
        ay  += __shfl_xor(ay, 16);  ay  += __shfl_xor(ay, 32);
        az0 += __shfl_xor(az0, 16); az0 += __shfl_xor(az0, 32);
        aw  += __shfl_xor(aw, 16);  aw  += __shfl_xor(aw, 32);
        const float inv = 1.f / (float)(deg > 0 ? deg : 1);
        const float4 av = make_float4(ax * inv, ay * inv, az0 * inv, aw * inv);
        const float4 xr = *(const float4*)&x[(size_t)n * 64 + jj];

        // h[lane] = relu(sum_k av[k]*W1l[k][lane] + xr[k]*W1r[k][lane] + b1)
        // av/xr component k lives in lane k>>2, element k&3 (compile-time).
        float hacc = b1v;
        #pragma unroll
        for (int k = 0; k < 64; ++k) {
            float ak, xk;
            switch (k & 3) {
                case 0: ak = __shfl(av.x, k >> 2); xk = __shfl(xr.x, k >> 2); break;
                case 1: ak = __shfl(av.y, k >> 2); xk = __shfl(xr.y, k >> 2); break;
                case 2: ak = __shfl(av.z, k >> 2); xk = __shfl(xr.z, k >> 2); break;
                default: ak = __shfl(av.w, k >> 2); xk = __shfl(xr.w, k >> 2); break;
            }
            hacc = fmaf(ak, w1l[k * 64 + lane], hacc);
            hacc = fmaf(xk, w1r[k * 64 + lane], hacc);
        }
        const float hval = hacc > 0.f ? hacc : 0.f;   // ReLU, stays in regs

        // z2 = h @ W2l, hw2r = h @ W2r (16 outs; groups split k, xor-combine)
        float azv = 0.f, arv = 0.f;
        #pragma unroll
        for (int i = 0; i < 16; ++i) {
            int   k  = g * 16 + i;
            float hk = __shfl(hval, k);
            azv = fmaf(hk, w2l[k * 17 + j], azv);
            arv = fmaf(hk, w2r[k * 17 + j], arv);
        }
        azv += __shfl_xor(azv, 16); azv += __shfl_xor(azv, 32);
        arv += __shfl_xor(arv, 16); arv += __shfl_xor(arv, 32);
        if (g == 0) {
            z2[(size_t)n * 16 + j]   = azv;
            hw2r[(size_t)n * 16 + j] = arv;
        }
    }
}

// ---------------------------------------------------------------------------
// k_l2: fused layer-2 gather + epilogue. Same group/unroll MLP structure:
//   out[n][j] = (sum z2[src][j]*w)/max(deg,1) + b2[j] + hw2r[n][j]
// ---------------------------------------------------------------------------
__global__ __launch_bounds__(256) void k_l2(const float* __restrict__ z2,
                                            const int* __restrict__ row_ptr,
                                            const uint2* __restrict__ csr,
                                            const float* __restrict__ b2,
                                            const float* __restrict__ hw2r,
                                            float* __restrict__ out) {
    const int lane = threadIdx.x & 63;
    const int wid  = blockIdx.x * 4 + (threadIdx.x >> 6);
    const int nw   = gridDim.x * 4;
    const int j = lane & 15, g = lane >> 4;
    for (int n = wid; n < N_NODES; n += nw) {
        const int r0 = row_ptr[n], r1 = row_ptr[n + 1];
        const int deg = r1 - r0;
        float a = 0.f;
        for (int i0 = r0; i0 < r1; i0 += 16) {
            const int rmax = r1 - 1;
            uint2 e[4]; float wt[4];
            #pragma unroll
            for (int u = 0; u < 4; ++u) {
                int idx = i0 + g + u * 4;
                int idc = idx < rmax ? idx : rmax;
                e[u]  = csr[idc];
                wt[u] = (idx < r1) ? __uint_as_float(e[u].y) : 0.f;
            }
            float zv[4];
            #pragma unroll
            for (int u = 0; u < 4; ++u)
                zv[u] = z2[(size_t)e[u].x * 16 + j];
            #pragma unroll
            for (int u = 0; u < 4; ++u) a = fmaf(zv[u], wt[u], a);
        }
        a += __shfl_xor(a, 16); a += __shfl_xor(a, 32);
        if (g == 0) {
            const float inv = 1.f / (float)(deg > 0 ? deg : 1);
            out[(size_t)n * 16 + j] = a * inv + b2[j] + hw2r[(size_t)n * 16 + j];
        }
    }
}

extern "C" void kernel_launch(void* const* d_in, const int* in_sizes, int n_in,
                              void* d_out, int out_size, void* d_ws, size_t ws_size,
                              hipStream_t stream) {
    const float* x   = (const float*)d_in[0];
    const int*   ei  = (const int*)d_in[1];   // [2, E]: row0=src, row1=dst
    const float* ew  = (const float*)d_in[2];
    const float* W1l = (const float*)d_in[3];
    const float* b1  = (const float*)d_in[4];
    const float* W1r = (const float*)d_in[5];
    const float* W2l = (const float*)d_in[6];
    const float* b2  = (const float*)d_in[7];
    const float* W2r = (const float*)d_in[8];
    float* out = (float*)d_out;

    // Workspace layout (csr first: 8B alignment at base).
    char* w = (char*)d_ws;
    uint2* csr     = (uint2*)w;  w += (size_t)N_EDGES * 8;
    float* z2      = (float*)w;  w += (size_t)N_NODES * 16 * 4;
    float* hw2r    = (float*)w;  w += (size_t)N_NODES * 16 * 4;
    int*   deg     = (int*)w;    w += (size_t)N_NODES * 4;
    int*   row_ptr = (int*)w;    w += (size_t)(N_NODES + 1) * 4;
    int*   cursor  = (int*)w;    w += (size_t)N_NODES * 4;
    int*   bsum    = (int*)w;    w += 128 * 4;
    int*   boff    = (int*)w;

    hipMemsetAsync(deg, 0, (size_t)N_NODES * 4, stream);

    k_hist <<<(N_EDGES + 255) / 256, 256, 0, stream>>>(ei, deg);
    k_scanA<<<NB_SCAN, 256, 0, stream>>>(deg, bsum);
    k_scanB<<<1, 64, 0, stream>>>(bsum, boff);
    k_scanC<<<NB_SCAN, 256, 0, stream>>>(deg, boff, row_ptr);
    hipMemcpyAsync(cursor, row_ptr, (size_t)N_NODES * 4,
                   hipMemcpyDeviceToDevice, stream);
    k_fill <<<(N_EDGES + 255) / 256, 256, 0, stream>>>(ei, ew, cursor, csr);
    k_l1   <<<512, 512, 0, stream>>>(x, row_ptr, csr, W1l, b1, W1r, W2l, W2r, z2, hw2r);
    k_l2   <<<1024, 256, 0, stream>>>(z2, row_ptr, csr, b2, hw2r, out);
}